// Round 21
// baseline (162.685 us; speedup 1.0000x reference)
//
#include <hip/hip_runtime.h>
#include <stdint.h>

// GAT: N=4096, F_in=512, H=8, F_out=64.
// P_ij = A_i·max(E1_j, R_i·E2_j)·adj, R_i = e^{-0.8 s_i}; A_i cancels in softmax.
// Round 21: proj rewritten as per-wave ALL-heads (X rows read once into xa[16],
// W streamed from L2; sd folded in as a 17th tile) -> X traffic 64->8MB, W 128->32MB,
// no LDS reduce. Pack threads emit 2 words (16 loads in flight). Both fused in one
// dispatch (32 proj blocks + 512 pack blocks) so the pack's HBM stream overlaps
// proj's MFMA grind. prep_w + gat (r16 register-direct quad-af) unchanged.

#define NN 4096
#define FIN 512
#define NH 8
#define FO 64

typedef _Float16 f16x8 __attribute__((ext_vector_type(8)));
typedef _Float16 f16x2 __attribute__((ext_vector_type(2)));
typedef __attribute__((ext_vector_type(4))) float f32x4;

union H8 { f16x8 v; f16x2 p[4]; unsigned u[4]; };
union U2 { unsigned u; f16x2 v; };

__device__ __forceinline__ unsigned short f2h(float f) {
  _Float16 h = (_Float16)f;               // RNE
  return __builtin_bit_cast(unsigned short, h);
}

__device__ __forceinline__ f16x8 ld_cvt8(const float* p) {   // f32x8 -> f16x8
  float4 a = *(const float4*)p, b = *(const float4*)(p + 4);
  f16x8 r;
  r[0] = (_Float16)a.x; r[1] = (_Float16)a.y; r[2] = (_Float16)a.z; r[3] = (_Float16)a.w;
  r[4] = (_Float16)b.x; r[5] = (_Float16)b.y; r[6] = (_Float16)b.z; r[7] = (_Float16)b.w;
  return r;
}

// ---------------- prep_w: W->WbT(fp16) coalesced-read + wa = W^T a (tiny) ---------
__global__ __launch_bounds__(256) void prep_w_kernel(
    const float* __restrict__ W, const float* __restrict__ a,
    unsigned short* __restrict__ WbT, unsigned short* __restrict__ WAh) {
  int bid = blockIdx.x, tid = threadIdx.x;
  if (bid < 1024) {                       // W[h][k][o] -> WbT[h][o][k], coalesced READ
    int item = bid * 256 + tid;           // 262144 items = (h,k,o)
    int o = item & 63, k = (item >> 6) & 511, h = item >> 15;
    WbT[h * 32768 + o * 512 + k] = f2h(W[h * 32768 + k * 64 + o]);
  } else {                                // wa[t][k] = sum_o W[h][k][o] * a[h][which*64+o]
    int item = (bid - 1024) * 256 + tid;  // 8192 items: t = h*2+which, k
    int h = item >> 10, which = (item >> 9) & 1, k = item & 511;
    const float4* wp = (const float4*)(W + ((size_t)h * FIN + k) * FO);
    const float4* ap = (const float4*)(a + h * 128 + which * 64);
    float s = 0.f;
#pragma unroll
    for (int o4 = 0; o4 < 16; ++o4) {
      float4 w4 = wp[o4], a4 = ap[o4];
      s += w4.x * a4.x + w4.y * a4.y + w4.z * a4.z + w4.w * a4.w;
    }
    WAh[(h * 2 + which) * FIN + k] = f2h(s);
  }
}

// ---------------- fused: proj all-heads bx<32 | adj-pack bx in [32,544) -----------
// D layout (16x16x32): col = lane&15, row = (lane>>4)*4 + reg   [m89]
__global__ __launch_bounds__(512, 3) void proj_pack_kernel(
    const float* __restrict__ X, const int* __restrict__ adj,
    const unsigned short* __restrict__ WbT, const unsigned short* __restrict__ WAh,
    unsigned short* __restrict__ Whfrag, float* __restrict__ Rf,
    unsigned short* __restrict__ E1h, unsigned short* __restrict__ E2h,
    unsigned* __restrict__ adjbitsT) {
  int bx = blockIdx.x;
  if (bx < 32) {                          // ---- proj: wave = 16-row tile, all heads
    int lane = threadIdx.x & 63, wave = threadIdx.x >> 6;
    int row16 = lane & 15, grp = lane >> 4;
    int rt = bx * 8 + wave;               // 0..255
    int i0 = rt * 16;
    const float* xb = X + (size_t)(i0 + row16) * FIN + grp * 8;
    f16x8 xa[16];                         // full K=512 of X rows, read ONCE
#pragma unroll
    for (int i = 0; i < 16; ++i) xa[i] = ld_cvt8(xb + i * 32);

    {                                     // sd tile: B = WAh (16 cols = (s,d)x8)
      const unsigned short* wb = WAh + row16 * FIN + grp * 8;
      f32x4 acc = {0, 0, 0, 0};
#pragma unroll
      for (int i = 0; i < 16; ++i)
        acc = __builtin_amdgcn_mfma_f32_16x16x32_f16(
            xa[i], *(const f16x8*)(wb + i * 32), acc, 0, 0, 0);
      int hh = row16 >> 1;
#pragma unroll
      for (int reg = 0; reg < 4; ++reg) {
        int rr = i0 + grp * 4 + reg;
        float v = acc[reg];
        if (row16 & 1) {                  // d -> col tables fp16, PRE-HALVED
          E1h[hh * NN + rr] = f2h(0.5f * __expf(v));
          E2h[hh * NN + rr] = f2h(0.5f * __expf(0.2f * v));
        } else {                          // s -> row table R = e^{-0.8 s}
          Rf[hh * NN + rr] = __expf(-0.8f * v);
        }
      }
    }
    // Whfrag mapping constants (same for every head)
    int jt = i0 >> 5;
    int kk0 = (i0 & 31) + grp * 4;
    int tl = (kk0 >> 3) * 16 + row16;
    int e0 = kk0 & 7;
#pragma unroll 1
    for (int h = 0; h < NH; ++h) {        // W streamed from L2-resident WbT
      const unsigned short* wb = WbT + h * (FO * FIN) + row16 * FIN + grp * 8;
      f32x4 acc[4] = {{0,0,0,0},{0,0,0,0},{0,0,0,0},{0,0,0,0}};
#pragma unroll
      for (int i = 0; i < 16; ++i) {
#pragma unroll
        for (int cb = 0; cb < 4; ++cb)
          acc[cb] = __builtin_amdgcn_mfma_f32_16x16x32_f16(
              xa[i], *(const f16x8*)(wb + cb * 16 * FIN + i * 32), acc[cb], 0, 0, 0);
      }
#pragma unroll
      for (int cb = 0; cb < 4; ++cb) {
        ushort4 pk;
        pk.x = f2h(acc[cb][0]); pk.y = f2h(acc[cb][1]);
        pk.z = f2h(acc[cb][2]); pk.w = f2h(acc[cb][3]);
        *(ushort4*)(Whfrag + (((size_t)h * 128 + jt) * 4 + cb) * 512 + tl * 8 + e0) = pk;
      }
    }
    return;
  }
  // ---- adj-pack: 2 words/thread, 16 independent int4 loads in flight ----
  int item = (bx - 32) * 512 + threadIdx.x;    // 262144 items = r*64 + jt2
  int r = item >> 6, jt2 = item & 63;
  const int4* p = (const int4*)(adj + (size_t)r * NN + jt2 * 64);
  unsigned w0 = 0, w1 = 0;
#pragma unroll
  for (int b = 0; b < 8; ++b) {
    int4 v = p[b];
    w0 |= (unsigned)(v.x & 1) << (4 * b);
    w0 |= (unsigned)(v.y & 1) << (4 * b + 1);
    w0 |= (unsigned)(v.z & 1) << (4 * b + 2);
    w0 |= (unsigned)(v.w & 1) << (4 * b + 3);
  }
#pragma unroll
  for (int b = 0; b < 8; ++b) {
    int4 v = p[8 + b];
    w1 |= (unsigned)(v.x & 1) << (4 * b);
    w1 |= (unsigned)(v.y & 1) << (4 * b + 1);
    w1 |= (unsigned)(v.z & 1) << (4 * b + 2);
    w1 |= (unsigned)(v.w & 1) << (4 * b + 3);
  }
  adjbitsT[(size_t)(jt2 * 2 + 0) * NN + r] = w0;   // scattered 4B stores
  adjbitsT[(size_t)(jt2 * 2 + 1) * NN + r] = w1;   // (fire-and-forget)
}

// ---------------- gat: register-direct quad-af (r16, unchanged) -------------------
struct Tile {
  f16x8 b0, b1, b2, b3;    // B-fragments (16 VGPR)
  f16x8 e1, e2;            // E tables    (8 VGPR)
  unsigned aw0, aw1, aw2, aw3;  // adj words per gi (4 VGPR)
};

__global__ __launch_bounds__(256, 2) void gat_kernel(
    const unsigned* __restrict__ adjbitsT, const unsigned short* __restrict__ Whfrag,
    const float* __restrict__ Rf, const unsigned short* __restrict__ E1h,
    const unsigned short* __restrict__ E2h, float* __restrict__ out) {
  __shared__ __align__(16) float red[3072];   // 12 KB reduce overlay
  int h = blockIdx.y;
  int lane = threadIdx.x & 63, jseg = threadIdx.x >> 6;
  int row16 = lane & 15, grp = lane >> 4;
  int r0 = blockIdx.x * 64;
  int jt0 = jseg * 32;

  f16x2 Rh[4];
#pragma unroll
  for (int gi = 0; gi < 4; ++gi) {
    _Float16 rv = (_Float16)Rf[h * NN + r0 + gi * 16 + row16];
    Rh[gi][0] = rv; Rh[gi][1] = rv;
  }

  H8 ones;
#pragma unroll
  for (int k = 0; k < 4; ++k) ones.u[k] = 0x3C003C00u;   // fp16 1.0 pairs

  const unsigned short* wsrc = Whfrag + (size_t)h * 262144 + (size_t)jt0 * 2048 + lane * 8;
  const unsigned short* e1p = E1h + h * NN + jt0 * 32 + grp * 8;
  const unsigned short* e2p = E2h + h * NN + jt0 * 32 + grp * 8;
  const unsigned* ap = adjbitsT + (size_t)jt0 * NN + r0 + row16;

  f32x4 acc[4][5];
#pragma unroll
  for (int gi = 0; gi < 4; ++gi)
#pragma unroll
    for (int cc = 0; cc < 5; ++cc) acc[gi][cc] = (f32x4){0, 0, 0, 0};

  auto ld = [&](int p, Tile& t) {          // 10 L2-hot loads -> VGPRs
    const unsigned short* bs = wsrc + (size_t)p * 2048;
    t.b0 = *(const f16x8*)(bs);
    t.b1 = *(const f16x8*)(bs + 512);
    t.b2 = *(const f16x8*)(bs + 1024);
    t.b3 = *(const f16x8*)(bs + 1536);
    t.e1 = *(const f16x8*)(e1p + p * 32);
    t.e2 = *(const f16x8*)(e2p + p * 32);
    const unsigned* aq = ap + (size_t)p * NN;
    t.aw0 = aq[0]; t.aw1 = aq[16]; t.aw2 = aq[32]; t.aw3 = aq[48];
  };

  auto compute = [&](const Tile& t) {
    H8 e1, e2;
    e1.v = t.e1; e2.v = t.e2;
    unsigned aw[4] = {t.aw0, t.aw1, t.aw2, t.aw3};
#pragma unroll
    for (int gi = 0; gi < 4; ++gi) {
      unsigned bb = (aw[gi] >> (grp * 8)) & 0xffu;
      unsigned tt = bb | (bb << 15);       // bit k at {k, k+15}
      H8 af;
#pragma unroll
      for (int k = 0; k < 4; ++k) {
        f16x2 mx = __builtin_elementwise_max(e1.p[k], Rh[gi] * e2.p[k]);
        U2 m;                              // bit2k->pos14, bit2k+1->pos30 (fp16 2.0)
        m.u = (tt << (14 - 2 * k)) & 0x40004000u;
        af.p[k] = mx * m.v;
      }
      acc[gi][0] = __builtin_amdgcn_mfma_f32_16x16x32_f16(af.v, t.b0, acc[gi][0], 0, 0, 0);
      acc[gi][1] = __builtin_amdgcn_mfma_f32_16x16x32_f16(af.v, t.b1, acc[gi][1], 0, 0, 0);
      acc[gi][2] = __builtin_amdgcn_mfma_f32_16x16x32_f16(af.v, t.b2, acc[gi][2], 0, 0, 0);
      acc[gi][3] = __builtin_amdgcn_mfma_f32_16x16x32_f16(af.v, t.b3, acc[gi][3], 0, 0, 0);
      acc[gi][4] = __builtin_amdgcn_mfma_f32_16x16x32_f16(af.v, ones.v, acc[gi][4], 0, 0, 0);
    }
  };

  // ---- barrier-free register pipeline: loads pinned above compute by mem-fence ----
  Tile tA, tB;
  ld(0, tA);
#pragma unroll 1
  for (int p2 = 0; p2 < 15; ++p2) {
    ld(2 * p2 + 1, tB);
    asm volatile("" ::: "memory");         // loads cannot sink below this point
    compute(tA);
    ld(2 * p2 + 2, tA);
    asm volatile("" ::: "memory");
    compute(tB);
  }
  ld(31, tB);
  compute(tA);
  compute(tB);

  // ---- chunked cross-jseg reduction (12 KB overlay, static indices) ----
  __syncthreads();
#pragma unroll
  for (int cc = 0; cc < 5; ++cc) {
    if (jseg != 0) {
#pragma unroll
      for (int gi = 0; gi < 4; ++gi)
        *(f32x4*)(red + (((jseg - 1) * 4 + gi) * 64 + lane) * 4) = acc[gi][cc];
    }
    __syncthreads();
    if (jseg == 0) {
#pragma unroll
      for (int s = 0; s < 3; ++s)
#pragma unroll
        for (int gi = 0; gi < 4; ++gi)
          acc[gi][cc] += *(const f32x4*)(red + ((s * 4 + gi) * 64 + lane) * 4);
    }
    __syncthreads();
  }

  if (jseg == 0) {
#pragma unroll
    for (int gi = 0; gi < 4; ++gi) {
#pragma unroll
      for (int reg = 0; reg < 4; ++reg) {
        float inv = 1.0f / acc[gi][4][reg];
        int row = r0 + gi * 16 + grp * 4 + reg;
        float* op = out + (size_t)row * (NH * FO) + h * FO + row16;
        op[0]  = acc[gi][0][reg] * inv;
        op[16] = acc[gi][1][reg] * inv;
        op[32] = acc[gi][2][reg] * inv;
        op[48] = acc[gi][3][reg] * inv;
      }
    }
  }
}

extern "C" void kernel_launch(void* const* d_in, const int* in_sizes, int n_in,
                              void* d_out, int out_size, void* d_ws, size_t ws_size,
                              hipStream_t stream) {
  const float* X  = (const float*)d_in[0];
  const int* adj  = (const int*)d_in[1];
  const float* W  = (const float*)d_in[2];
  const float* a  = (const float*)d_in[3];
  float* out = (float*)d_out;
  char* ws = (char*)d_ws;

  unsigned short* WbT    = (unsigned short*)(ws + 0);          // 512 KB
  unsigned* adjbitsT     = (unsigned*)(ws + 524288);           // 2 MB
  unsigned short* Whfrag = (unsigned short*)(ws + 2621440);    // 4 MB
  unsigned short* WAh    = (unsigned short*)(ws + 6815744);    // 16 KB
  float* Rf              = (float*)(ws + 6832128);             // 128 KB
  unsigned short* E1h    = (unsigned short*)(ws + 6963200);    // 64 KB
  unsigned short* E2h    = (unsigned short*)(ws + 7028736);    // 64 KB (total ~6.8 MB)

  prep_w_kernel<<<1056, 256, 0, stream>>>(W, a, WbT, WAh);
  proj_pack_kernel<<<544, 512, 0, stream>>>(X, adj, WbT, WAh, Whfrag, Rf, E1h, E2h,
                                            adjbitsT);
  gat_kernel<<<dim3(64, 8), 256, 0, stream>>>(adjbitsT, Whfrag, Rf, E1h, E2h, out);
}

// Round 22
// 91.111 us; speedup vs baseline: 1.7856x; 1.7856x over previous
//
#include <hip/hip_runtime.h>
#include <stdint.h>

// GAT: N=4096, F_in=512, H=8, F_out=64.
// P_ij = A_i·max(E1_j, R_i·E2_j)·adj, R_i = e^{-0.8 s_i}; A_i cancels in softmax.
// Round 22: adjbits layout flipped to ROW-MAJOR [r][jt] -> pack has coalesced reads
// AND coalesced writes (no transpose, no scatter side at all). gat reads the 2MB
// L2-resident table at lane-stride 512B (16 lines/instr, trivial). Base = r19
// fused structure; proj/prep_w/gat-core unchanged.

#define NN 4096
#define FIN 512
#define NH 8
#define FO 64

typedef _Float16 f16x8 __attribute__((ext_vector_type(8)));
typedef _Float16 f16x2 __attribute__((ext_vector_type(2)));
typedef __attribute__((ext_vector_type(4))) float f32x4;

union H8 { f16x8 v; f16x2 p[4]; unsigned u[4]; };
union U2 { unsigned u; f16x2 v; };

__device__ __forceinline__ unsigned short f2h(float f) {
  _Float16 h = (_Float16)f;               // RNE
  return __builtin_bit_cast(unsigned short, h);
}

__device__ __forceinline__ f16x8 ld_cvt8(const float* p) {   // f32x8 -> f16x8
  float4 a = *(const float4*)p, b = *(const float4*)(p + 4);
  f16x8 r;
  r[0] = (_Float16)a.x; r[1] = (_Float16)a.y; r[2] = (_Float16)a.z; r[3] = (_Float16)a.w;
  r[4] = (_Float16)b.x; r[5] = (_Float16)b.y; r[6] = (_Float16)b.z; r[7] = (_Float16)b.w;
  return r;
}

// ---------------- prep_w: W->WbT(fp16) coalesced-read + wa = W^T a (tiny) ---------
__global__ __launch_bounds__(256) void prep_w_kernel(
    const float* __restrict__ W, const float* __restrict__ a,
    unsigned short* __restrict__ WbT, unsigned short* __restrict__ WAh) {
  int bid = blockIdx.x, tid = threadIdx.x;
  if (bid < 1024) {                       // W[h][k][o] -> WbT[h][o][k], coalesced READ
    int item = bid * 256 + tid;           // 262144 items = (h,k,o)
    int o = item & 63, k = (item >> 6) & 511, h = item >> 15;
    WbT[h * 32768 + o * 512 + k] = f2h(W[h * 32768 + k * 64 + o]);
  } else {                                // wa[t][k] = sum_o W[h][k][o] * a[h][which*64+o]
    int item = (bid - 1024) * 256 + tid;  // 8192 items: t = h*2+which, k
    int h = item >> 10, which = (item >> 9) & 1, k = item & 511;
    const float4* wp = (const float4*)(W + ((size_t)h * FIN + k) * FO);
    const float4* ap = (const float4*)(a + h * 128 + which * 64);
    float s = 0.f;
#pragma unroll
    for (int o4 = 0; o4 < 16; ++o4) {
      float4 w4 = wp[o4], a4 = ap[o4];
      s += w4.x * a4.x + w4.y * a4.y + w4.z * a4.z + w4.w * a4.w;
    }
    WAh[(h * 2 + which) * FIN + k] = f2h(s);
  }
}

// ---------------- fused: proj (+sd) bx<544 | adj-pack bx>=544 ---------------------
// D layout (16x16x32): col = lane&15, row = (lane>>4)*4 + reg   [m89]
__global__ __launch_bounds__(512, 4) void proj_adj_kernel(
    const float* __restrict__ X, const int* __restrict__ adj,
    const unsigned short* __restrict__ WbT, const unsigned short* __restrict__ WAh,
    unsigned short* __restrict__ Whfrag, float* __restrict__ Rf,
    unsigned short* __restrict__ E1h, unsigned short* __restrict__ E2h,
    unsigned* __restrict__ adjbits) {
  __shared__ float red[4 * 64 * 20];      // 20KB partial store (proj blocks only)
  int lane = threadIdx.x & 63, wave = threadIdx.x >> 6;
  int row16 = lane & 15, grp = lane >> 4;
  int bx = blockIdx.x;
  if (bx >= 544) {                        // ---- adj-pack: coalesced reads AND writes
    int item = (bx - 544) * 512 + threadIdx.x;   // item = r*128 + jt
    int r = item >> 7, jt = item & 127;          // lane-consecutive jt
    const int4* p = (const int4*)(adj + (size_t)r * NN + jt * 32);
    unsigned bits = 0;
#pragma unroll
    for (int b = 0; b < 8; ++b) {                // 8 contiguous int4s, all in flight
      int4 v = p[b];
      bits |= (unsigned)(v.x & 1) << (4 * b);
      bits |= (unsigned)(v.y & 1) << (4 * b + 1);
      bits |= (unsigned)(v.z & 1) << (4 * b + 2);
      bits |= (unsigned)(v.w & 1) << (4 * b + 3);
    }
    adjbits[item] = bits;                        // row-major [r][jt]: COALESCED store
    return;
  }
  if (bx >= 512) {                        // sd: [s,d]x8 = X @ WA  (16 cols, K=512)
    int i0 = ((bx - 512) * 8 + wave) * 16;
    if (i0 >= NN) return;
    f32x4 acc = {0, 0, 0, 0};
    const float* xb = X + (size_t)(i0 + row16) * FIN + grp * 8;
    const unsigned short* wb = WAh + row16 * FIN + grp * 8;
#pragma unroll
    for (int k0 = 0; k0 < FIN; k0 += 32)
      acc = __builtin_amdgcn_mfma_f32_16x16x32_f16(ld_cvt8(xb + k0),
                                                   *(const f16x8*)(wb + k0), acc, 0, 0, 0);
    int hh = row16 >> 1;
#pragma unroll
    for (int reg = 0; reg < 4; ++reg) {
      int rr = i0 + grp * 4 + reg;
      float v = acc[reg];
      if (row16 & 1) {                    // d -> col tables fp16, PRE-HALVED
        E1h[hh * NN + rr] = f2h(0.5f * __expf(v));
        E2h[hh * NN + rr] = f2h(0.5f * __expf(0.2f * v));
      } else {                            // s -> row table R = e^{-0.8 s}
        Rf[hh * NN + rr] = __expf(-0.8f * v);
      }
    }
    return;
  }
  int kh = wave >> 2, jb = wave & 3;
  int job = bx * 4 + jb;                  // 2048 jobs = 256 rowtiles x 8 heads
  int h = job & 7, rt = job >> 3;
  int i0 = rt * 16;
  f32x4 acc[4] = {{0,0,0,0},{0,0,0,0},{0,0,0,0},{0,0,0,0}};
  const float* xb = X + (size_t)(i0 + row16) * FIN + kh * 256 + grp * 8;
  const unsigned short* wb = WbT + h * (FO * FIN) + row16 * FIN + kh * 256 + grp * 8;
#pragma unroll
  for (int k0 = 0; k0 < 256; k0 += 32) {
    f16x8 af = ld_cvt8(xb + k0);
#pragma unroll
    for (int cb = 0; cb < 4; ++cb)
      acc[cb] = __builtin_amdgcn_mfma_f32_16x16x32_f16(
          af, *(const f16x8*)(wb + cb * 16 * FIN + k0), acc[cb], 0, 0, 0);
  }
  if (kh == 1) {
    float* q = red + (jb * 64 + lane) * 20;
#pragma unroll
    for (int cb = 0; cb < 4; ++cb) *(f32x4*)(q + cb * 4) = acc[cb];
  }
  __syncthreads();
  if (kh == 0) {
    const float* q = red + (jb * 64 + lane) * 20;
#pragma unroll
    for (int cb = 0; cb < 4; ++cb) acc[cb] += *(const f32x4*)(q + cb * 4);
    // Whfrag[h][jt][cb][l][e] = Wh[jt*32 + (l>>4)*8 + e][cb*16 + (l&15)]
    int jt = i0 >> 5;
    int kk0 = (i0 & 31) + grp * 4;
    int tl = (kk0 >> 3) * 16 + row16;
    int e0 = kk0 & 7;
#pragma unroll
    for (int cb = 0; cb < 4; ++cb) {
      ushort4 pk;
      pk.x = f2h(acc[cb][0]); pk.y = f2h(acc[cb][1]);
      pk.z = f2h(acc[cb][2]); pk.w = f2h(acc[cb][3]);
      *(ushort4*)(Whfrag + (((size_t)h * 128 + jt) * 4 + cb) * 512 + tl * 8 + e0) = pk;
    }
  }
}

// ---------------- gat: register-direct quad-af; adj reads from row-major table ----
struct Tile {
  f16x8 b0, b1, b2, b3;    // B-fragments (16 VGPR)
  f16x8 e1, e2;            // E tables    (8 VGPR)
  unsigned aw0, aw1, aw2, aw3;  // adj words per gi (4 VGPR)
};

__global__ __launch_bounds__(256, 2) void gat_kernel(
    const unsigned* __restrict__ adjbits, const unsigned short* __restrict__ Whfrag,
    const float* __restrict__ Rf, const unsigned short* __restrict__ E1h,
    const unsigned short* __restrict__ E2h, float* __restrict__ out) {
  __shared__ __align__(16) float red[3072];   // 12 KB reduce overlay
  int h = blockIdx.y;
  int lane = threadIdx.x & 63, jseg = threadIdx.x >> 6;
  int row16 = lane & 15, grp = lane >> 4;
  int r0 = blockIdx.x * 64;
  int jt0 = jseg * 32;

  f16x2 Rh[4];
#pragma unroll
  for (int gi = 0; gi < 4; ++gi) {
    _Float16 rv = (_Float16)Rf[h * NN + r0 + gi * 16 + row16];
    Rh[gi][0] = rv; Rh[gi][1] = rv;
  }

  H8 ones;
#pragma unroll
  for (int k = 0; k < 4; ++k) ones.u[k] = 0x3C003C00u;   // fp16 1.0 pairs

  const unsigned short* wsrc = Whfrag + (size_t)h * 262144 + (size_t)jt0 * 2048 + lane * 8;
  const unsigned short* e1p = E1h + h * NN + jt0 * 32 + grp * 8;
  const unsigned short* e2p = E2h + h * NN + jt0 * 32 + grp * 8;
  const unsigned* ap = adjbits + (size_t)(r0 + row16) * 128 + jt0;   // row-major [r][jt]

  f32x4 acc[4][5];
#pragma unroll
  for (int gi = 0; gi < 4; ++gi)
#pragma unroll
    for (int cc = 0; cc < 5; ++cc) acc[gi][cc] = (f32x4){0, 0, 0, 0};

  auto ld = [&](int p, Tile& t) {          // 10 L2-hot loads -> VGPRs
    const unsigned short* bs = wsrc + (size_t)p * 2048;
    t.b0 = *(const f16x8*)(bs);
    t.b1 = *(const f16x8*)(bs + 512);
    t.b2 = *(const f16x8*)(bs + 1024);
    t.b3 = *(const f16x8*)(bs + 1536);
    t.e1 = *(const f16x8*)(e1p + p * 32);
    t.e2 = *(const f16x8*)(e2p + p * 32);
    const unsigned* aq = ap + p;           // stride 512B across the 16 row16-lanes
    t.aw0 = aq[0];
    t.aw1 = aq[16 * 128];
    t.aw2 = aq[32 * 128];
    t.aw3 = aq[48 * 128];
  };

  auto compute = [&](const Tile& t) {
    H8 e1, e2;
    e1.v = t.e1; e2.v = t.e2;
    unsigned aw[4] = {t.aw0, t.aw1, t.aw2, t.aw3};
#pragma unroll
    for (int gi = 0; gi < 4; ++gi) {
      unsigned bb = (aw[gi] >> (grp * 8)) & 0xffu;
      unsigned tt = bb | (bb << 15);       // bit k at {k, k+15}
      H8 af;
#pragma unroll
      for (int k = 0; k < 4; ++k) {
        f16x2 mx = __builtin_elementwise_max(e1.p[k], Rh[gi] * e2.p[k]);
        U2 m;                              // bit2k->pos14, bit2k+1->pos30 (fp16 2.0)
        m.u = (tt << (14 - 2 * k)) & 0x40004000u;
        af.p[k] = mx * m.v;
      }
      acc[gi][0] = __builtin_amdgcn_mfma_f32_16x16x32_f16(af.v, t.b0, acc[gi][0], 0, 0, 0);
      acc[gi][1] = __builtin_amdgcn_mfma_f32_16x16x32_f16(af.v, t.b1, acc[gi][1], 0, 0, 0);
      acc[gi][2] = __builtin_amdgcn_mfma_f32_16x16x32_f16(af.v, t.b2, acc[gi][2], 0, 0, 0);
      acc[gi][3] = __builtin_amdgcn_mfma_f32_16x16x32_f16(af.v, t.b3, acc[gi][3], 0, 0, 0);
      acc[gi][4] = __builtin_amdgcn_mfma_f32_16x16x32_f16(af.v, ones.v, acc[gi][4], 0, 0, 0);
    }
  };

  // ---- barrier-free register pipeline: loads pinned above compute by mem-fence ----
  Tile tA, tB;
  ld(0, tA);
#pragma unroll 1
  for (int p2 = 0; p2 < 15; ++p2) {
    ld(2 * p2 + 1, tB);
    asm volatile("" ::: "memory");         // loads cannot sink below this point
    compute(tA);
    ld(2 * p2 + 2, tA);
    asm volatile("" ::: "memory");
    compute(tB);
  }
  ld(31, tB);
  compute(tA);
  compute(tB);

  // ---- chunked cross-jseg reduction (12 KB overlay, static indices) ----
  __syncthreads();
#pragma unroll
  for (int cc = 0; cc < 5; ++cc) {
    if (jseg != 0) {
#pragma unroll
      for (int gi = 0; gi < 4; ++gi)
        *(f32x4*)(red + (((jseg - 1) * 4 + gi) * 64 + lane) * 4) = acc[gi][cc];
    }
    __syncthreads();
    if (jseg == 0) {
#pragma unroll
      for (int s = 0; s < 3; ++s)
#pragma unroll
        for (int gi = 0; gi < 4; ++gi)
          acc[gi][cc] += *(const f32x4*)(red + ((s * 4 + gi) * 64 + lane) * 4);
    }
    __syncthreads();
  }

  if (jseg == 0) {
#pragma unroll
    for (int gi = 0; gi < 4; ++gi) {
#pragma unroll
      for (int reg = 0; reg < 4; ++reg) {
        float inv = 1.0f / acc[gi][4][reg];
        int row = r0 + gi * 16 + grp * 4 + reg;
        float* op = out + (size_t)row * (NH * FO) + h * FO + row16;
        op[0]  = acc[gi][0][reg] * inv;
        op[16] = acc[gi][1][reg] * inv;
        op[32] = acc[gi][2][reg] * inv;
        op[48] = acc[gi][3][reg] * inv;
      }
    }
  }
}

extern "C" void kernel_launch(void* const* d_in, const int* in_sizes, int n_in,
                              void* d_out, int out_size, void* d_ws, size_t ws_size,
                              hipStream_t stream) {
  const float* X  = (const float*)d_in[0];
  const int* adj  = (const int*)d_in[1];
  const float* W  = (const float*)d_in[2];
  const float* a  = (const float*)d_in[3];
  float* out = (float*)d_out;
  char* ws = (char*)d_ws;

  unsigned short* WbT    = (unsigned short*)(ws + 0);          // 512 KB
  unsigned* adjbits      = (unsigned*)(ws + 524288);           // 2 MB, row-major [r][jt]
  unsigned short* Whfrag = (unsigned short*)(ws + 2621440);    // 4 MB
  unsigned short* WAh    = (unsigned short*)(ws + 6815744);    // 16 KB
  float* Rf              = (float*)(ws + 6832128);             // 128 KB
  unsigned short* E1h    = (unsigned short*)(ws + 6963200);    // 64 KB
  unsigned short* E2h    = (unsigned short*)(ws + 7028736);    // 64 KB (total ~6.8 MB)

  prep_w_kernel<<<1056, 256, 0, stream>>>(W, a, WbT, WAh);
  proj_adj_kernel<<<1568, 512, 0, stream>>>(X, adj, WbT, WAh, Whfrag, Rf, E1h, E2h,
                                            adjbits);
  gat_kernel<<<dim3(64, 8), 256, 0, stream>>>(adjbits, Whfrag, Rf, E1h, E2h, out);
}

// Round 23
// 75.747 us; speedup vs baseline: 2.1478x; 1.2028x over previous
//
#include <hip/hip_runtime.h>
#include <stdint.h>

// GAT: N=4096, F_in=512, H=8, F_out=64.
// P_ij = A_i·max(E1_j, R_i·E2_j)·adj, R_i = e^{-0.8 s_i}; A_i cancels in softmax.
// Round 23: keep r22's fully-coalesced row-major adj-pack; gat stages its 32KB
// adj slice (rows r0..63 x 128 words) into LDS once per block with coalesced
// reads, padded to 132 words/row (bank = row*4+jt mod 32 -> 2-way, free).
// Main-loop adj access = conflict-free ds_read. Rest identical to r22.

#define NN 4096
#define FIN 512
#define NH 8
#define FO 64

typedef _Float16 f16x8 __attribute__((ext_vector_type(8)));
typedef _Float16 f16x2 __attribute__((ext_vector_type(2)));
typedef __attribute__((ext_vector_type(4))) float f32x4;

union H8 { f16x8 v; f16x2 p[4]; unsigned u[4]; };
union U2 { unsigned u; f16x2 v; };

__device__ __forceinline__ unsigned short f2h(float f) {
  _Float16 h = (_Float16)f;               // RNE
  return __builtin_bit_cast(unsigned short, h);
}

__device__ __forceinline__ f16x8 ld_cvt8(const float* p) {   // f32x8 -> f16x8
  float4 a = *(const float4*)p, b = *(const float4*)(p + 4);
  f16x8 r;
  r[0] = (_Float16)a.x; r[1] = (_Float16)a.y; r[2] = (_Float16)a.z; r[3] = (_Float16)a.w;
  r[4] = (_Float16)b.x; r[5] = (_Float16)b.y; r[6] = (_Float16)b.z; r[7] = (_Float16)b.w;
  return r;
}

// ---------------- prep_w: W->WbT(fp16) coalesced-read + wa = W^T a (tiny) ---------
__global__ __launch_bounds__(256) void prep_w_kernel(
    const float* __restrict__ W, const float* __restrict__ a,
    unsigned short* __restrict__ WbT, unsigned short* __restrict__ WAh) {
  int bid = blockIdx.x, tid = threadIdx.x;
  if (bid < 1024) {                       // W[h][k][o] -> WbT[h][o][k], coalesced READ
    int item = bid * 256 + tid;           // 262144 items = (h,k,o)
    int o = item & 63, k = (item >> 6) & 511, h = item >> 15;
    WbT[h * 32768 + o * 512 + k] = f2h(W[h * 32768 + k * 64 + o]);
  } else {                                // wa[t][k] = sum_o W[h][k][o] * a[h][which*64+o]
    int item = (bid - 1024) * 256 + tid;  // 8192 items: t = h*2+which, k
    int h = item >> 10, which = (item >> 9) & 1, k = item & 511;
    const float4* wp = (const float4*)(W + ((size_t)h * FIN + k) * FO);
    const float4* ap = (const float4*)(a + h * 128 + which * 64);
    float s = 0.f;
#pragma unroll
    for (int o4 = 0; o4 < 16; ++o4) {
      float4 w4 = wp[o4], a4 = ap[o4];
      s += w4.x * a4.x + w4.y * a4.y + w4.z * a4.z + w4.w * a4.w;
    }
    WAh[(h * 2 + which) * FIN + k] = f2h(s);
  }
}

// ---------------- fused: proj (+sd) bx<544 | adj-pack bx>=544 ---------------------
// D layout (16x16x32): col = lane&15, row = (lane>>4)*4 + reg   [m89]
__global__ __launch_bounds__(512, 4) void proj_adj_kernel(
    const float* __restrict__ X, const int* __restrict__ adj,
    const unsigned short* __restrict__ WbT, const unsigned short* __restrict__ WAh,
    unsigned short* __restrict__ Whfrag, float* __restrict__ Rf,
    unsigned short* __restrict__ E1h, unsigned short* __restrict__ E2h,
    unsigned* __restrict__ adjbits) {
  __shared__ float red[4 * 64 * 20];      // 20KB partial store (proj blocks only)
  int lane = threadIdx.x & 63, wave = threadIdx.x >> 6;
  int row16 = lane & 15, grp = lane >> 4;
  int bx = blockIdx.x;
  if (bx >= 544) {                        // ---- adj-pack: coalesced reads AND writes
    int item = (bx - 544) * 512 + threadIdx.x;   // item = r*128 + jt
    int r = item >> 7, jt = item & 127;          // lane-consecutive jt
    const int4* p = (const int4*)(adj + (size_t)r * NN + jt * 32);
    unsigned bits = 0;
#pragma unroll
    for (int b = 0; b < 8; ++b) {                // 8 contiguous int4s, all in flight
      int4 v = p[b];
      bits |= (unsigned)(v.x & 1) << (4 * b);
      bits |= (unsigned)(v.y & 1) << (4 * b + 1);
      bits |= (unsigned)(v.z & 1) << (4 * b + 2);
      bits |= (unsigned)(v.w & 1) << (4 * b + 3);
    }
    adjbits[item] = bits;                        // row-major [r][jt]: COALESCED store
    return;
  }
  if (bx >= 512) {                        // sd: [s,d]x8 = X @ WA  (16 cols, K=512)
    int i0 = ((bx - 512) * 8 + wave) * 16;
    if (i0 >= NN) return;
    f32x4 acc = {0, 0, 0, 0};
    const float* xb = X + (size_t)(i0 + row16) * FIN + grp * 8;
    const unsigned short* wb = WAh + row16 * FIN + grp * 8;
#pragma unroll
    for (int k0 = 0; k0 < FIN; k0 += 32)
      acc = __builtin_amdgcn_mfma_f32_16x16x32_f16(ld_cvt8(xb + k0),
                                                   *(const f16x8*)(wb + k0), acc, 0, 0, 0);
    int hh = row16 >> 1;
#pragma unroll
    for (int reg = 0; reg < 4; ++reg) {
      int rr = i0 + grp * 4 + reg;
      float v = acc[reg];
      if (row16 & 1) {                    // d -> col tables fp16, PRE-HALVED
        E1h[hh * NN + rr] = f2h(0.5f * __expf(v));
        E2h[hh * NN + rr] = f2h(0.5f * __expf(0.2f * v));
      } else {                            // s -> row table R = e^{-0.8 s}
        Rf[hh * NN + rr] = __expf(-0.8f * v);
      }
    }
    return;
  }
  int kh = wave >> 2, jb = wave & 3;
  int job = bx * 4 + jb;                  // 2048 jobs = 256 rowtiles x 8 heads
  int h = job & 7, rt = job >> 3;
  int i0 = rt * 16;
  f32x4 acc[4] = {{0,0,0,0},{0,0,0,0},{0,0,0,0},{0,0,0,0}};
  const float* xb = X + (size_t)(i0 + row16) * FIN + kh * 256 + grp * 8;
  const unsigned short* wb = WbT + h * (FO * FIN) + row16 * FIN + kh * 256 + grp * 8;
#pragma unroll
  for (int k0 = 0; k0 < 256; k0 += 32) {
    f16x8 af = ld_cvt8(xb + k0);
#pragma unroll
    for (int cb = 0; cb < 4; ++cb)
      acc[cb] = __builtin_amdgcn_mfma_f32_16x16x32_f16(
          af, *(const f16x8*)(wb + cb * 16 * FIN + k0), acc[cb], 0, 0, 0);
  }
  if (kh == 1) {
    float* q = red + (jb * 64 + lane) * 20;
#pragma unroll
    for (int cb = 0; cb < 4; ++cb) *(f32x4*)(q + cb * 4) = acc[cb];
  }
  __syncthreads();
  if (kh == 0) {
    const float* q = red + (jb * 64 + lane) * 20;
#pragma unroll
    for (int cb = 0; cb < 4; ++cb) acc[cb] += *(const f32x4*)(q + cb * 4);
    // Whfrag[h][jt][cb][l][e] = Wh[jt*32 + (l>>4)*8 + e][cb*16 + (l&15)]
    int jt = i0 >> 5;
    int kk0 = (i0 & 31) + grp * 4;
    int tl = (kk0 >> 3) * 16 + row16;
    int e0 = kk0 & 7;
#pragma unroll
    for (int cb = 0; cb < 4; ++cb) {
      ushort4 pk;
      pk.x = f2h(acc[cb][0]); pk.y = f2h(acc[cb][1]);
      pk.z = f2h(acc[cb][2]); pk.w = f2h(acc[cb][3]);
      *(ushort4*)(Whfrag + (((size_t)h * 128 + jt) * 4 + cb) * 512 + tl * 8 + e0) = pk;
    }
  }
}

// ---------------- gat: register-direct quad-af; adj staged to padded LDS ----------
struct Tile {
  f16x8 b0, b1, b2, b3;    // B-fragments (16 VGPR)
  f16x8 e1, e2;            // E tables    (8 VGPR)
};

#define ROWW 132            // padded words/row: bank = (row*4 + jt) % 32 -> 2-way free

__global__ __launch_bounds__(256, 2) void gat_kernel(
    const unsigned* __restrict__ adjbits, const unsigned short* __restrict__ Whfrag,
    const float* __restrict__ Rf, const unsigned short* __restrict__ E1h,
    const unsigned short* __restrict__ E2h, float* __restrict__ out) {
  __shared__ __align__(16) char lds[64 * ROWW * 4];   // 33792 B: adj stage / reduce overlay
  unsigned* la = (unsigned*)lds;
  int h = blockIdx.y;
  int lane = threadIdx.x & 63, jseg = threadIdx.x >> 6;
  int row16 = lane & 15, grp = lane >> 4;
  int r0 = blockIdx.x * 64;
  int jt0 = jseg * 32;

  // ---- stage adj rows r0..r0+63 (row-major, 128 words each) -> LDS, coalesced ----
  {
    int row = threadIdx.x >> 2, seg = threadIdx.x & 3;   // thread reads 128B row-chunk
    const uint4* src = (const uint4*)(adjbits + (size_t)(r0 + row) * 128 + seg * 32);
    uint4* dst = (uint4*)(la + row * ROWW + seg * 32);
#pragma unroll
    for (int i = 0; i < 8; ++i) dst[i] = src[i];
  }

  f16x2 Rh[4];
#pragma unroll
  for (int gi = 0; gi < 4; ++gi) {
    _Float16 rv = (_Float16)Rf[h * NN + r0 + gi * 16 + row16];
    Rh[gi][0] = rv; Rh[gi][1] = rv;
  }

  H8 ones;
#pragma unroll
  for (int k = 0; k < 4; ++k) ones.u[k] = 0x3C003C00u;   // fp16 1.0 pairs

  const unsigned short* wsrc = Whfrag + (size_t)h * 262144 + (size_t)jt0 * 2048 + lane * 8;
  const unsigned short* e1p = E1h + h * NN + jt0 * 32 + grp * 8;
  const unsigned short* e2p = E2h + h * NN + jt0 * 32 + grp * 8;

  f32x4 acc[4][5];
#pragma unroll
  for (int gi = 0; gi < 4; ++gi)
#pragma unroll
    for (int cc = 0; cc < 5; ++cc) acc[gi][cc] = (f32x4){0, 0, 0, 0};

  __syncthreads();                        // adj stage visible to all waves

  auto ld = [&](int p, Tile& t) {          // 6 L2-hot loads -> VGPRs
    const unsigned short* bs = wsrc + (size_t)p * 2048;
    t.b0 = *(const f16x8*)(bs);
    t.b1 = *(const f16x8*)(bs + 512);
    t.b2 = *(const f16x8*)(bs + 1024);
    t.b3 = *(const f16x8*)(bs + 1536);
    t.e1 = *(const f16x8*)(e1p + p * 32);
    t.e2 = *(const f16x8*)(e2p + p * 32);
  };

  auto compute = [&](int p, const Tile& t) {
    H8 e1, e2;
    e1.v = t.e1; e2.v = t.e2;
    int jt = jt0 + p;
#pragma unroll
    for (int gi = 0; gi < 4; ++gi) {
      unsigned bw = la[(gi * 16 + row16) * ROWW + jt];   // conflict-free ds_read
      unsigned bb = (bw >> (grp * 8)) & 0xffu;
      unsigned tt = bb | (bb << 15);       // bit k at {k, k+15}
      H8 af;
#pragma unroll
      for (int k = 0; k < 4; ++k) {
        f16x2 mx = __builtin_elementwise_max(e1.p[k], Rh[gi] * e2.p[k]);
        U2 m;                              // bit2k->pos14, bit2k+1->pos30 (fp16 2.0)
        m.u = (tt << (14 - 2 * k)) & 0x40004000u;
        af.p[k] = mx * m.v;
      }
      acc[gi][0] = __builtin_amdgcn_mfma_f32_16x16x32_f16(af.v, t.b0, acc[gi][0], 0, 0, 0);
      acc[gi][1] = __builtin_amdgcn_mfma_f32_16x16x32_f16(af.v, t.b1, acc[gi][1], 0, 0, 0);
      acc[gi][2] = __builtin_amdgcn_mfma_f32_16x16x32_f16(af.v, t.b2, acc[gi][2], 0, 0, 0);
      acc[gi][3] = __builtin_amdgcn_mfma_f32_16x16x32_f16(af.v, t.b3, acc[gi][3], 0, 0, 0);
      acc[gi][4] = __builtin_amdgcn_mfma_f32_16x16x32_f16(af.v, ones.v, acc[gi][4], 0, 0, 0);
    }
  };

  // ---- barrier-free register pipeline: loads pinned above compute by mem-fence ----
  Tile tA, tB;
  ld(0, tA);
#pragma unroll 1
  for (int p2 = 0; p2 < 15; ++p2) {
    ld(2 * p2 + 1, tB);
    asm volatile("" ::: "memory");         // loads cannot sink below this point
    compute(2 * p2, tA);
    ld(2 * p2 + 2, tA);
    asm volatile("" ::: "memory");
    compute(2 * p2 + 1, tB);
  }
  ld(31, tB);
  compute(30, tA);
  compute(31, tB);

  // ---- chunked cross-jseg reduction (overlay onto adj LDS, static indices) ----
  __syncthreads();
  float* red = (float*)lds;               // 12 KB of the 33 KB
#pragma unroll
  for (int cc = 0; cc < 5; ++cc) {
    if (jseg != 0) {
#pragma unroll
      for (int gi = 0; gi < 4; ++gi)
        *(f32x4*)(red + (((jseg - 1) * 4 + gi) * 64 + lane) * 4) = acc[gi][cc];
    }
    __syncthreads();
    if (jseg == 0) {
#pragma unroll
      for (int s = 0; s < 3; ++s)
#pragma unroll
        for (int gi = 0; gi < 4; ++gi)
          acc[gi][cc] += *(const f32x4*)(red + ((s * 4 + gi) * 64 + lane) * 4);
    }
    __syncthreads();
  }

  if (jseg == 0) {
#pragma unroll
    for (int gi = 0; gi < 4; ++gi) {
#pragma unroll
      for (int reg = 0; reg < 4; ++reg) {
        float inv = 1.0f / acc[gi][4][reg];
        int row = r0 + gi * 16 + grp * 4 + reg;
        float* op = out + (size_t)row * (NH * FO) + h * FO + row16;
        op[0]  = acc[gi][0][reg] * inv;
        op[16] = acc[gi][1][reg] * inv;
        op[32] = acc[gi][2][reg] * inv;
        op[48] = acc[gi][3][reg] * inv;
      }
    }
  }
}

extern "C" void kernel_launch(void* const* d_in, const int* in_sizes, int n_in,
                              void* d_out, int out_size, void* d_ws, size_t ws_size,
                              hipStream_t stream) {
  const float* X  = (const float*)d_in[0];
  const int* adj  = (const int*)d_in[1];
  const float* W  = (const float*)d_in[2];
  const float* a  = (const float*)d_in[3];
  float* out = (float*)d_out;
  char* ws = (char*)d_ws;

  unsigned short* WbT    = (unsigned short*)(ws + 0);          // 512 KB
  unsigned* adjbits      = (unsigned*)(ws + 524288);           // 2 MB, row-major [r][jt]
  unsigned short* Whfrag = (unsigned short*)(ws + 2621440);    // 4 MB
  unsigned short* WAh    = (unsigned short*)(ws + 6815744);    // 16 KB
  float* Rf              = (float*)(ws + 6832128);             // 128 KB
  unsigned short* E1h    = (unsigned short*)(ws + 6963200);    // 64 KB
  unsigned short* E2h    = (unsigned short*)(ws + 7028736);    // 64 KB (total ~6.8 MB)

  prep_w_kernel<<<1056, 256, 0, stream>>>(W, a, WbT, WAh);
  proj_adj_kernel<<<1568, 512, 0, stream>>>(X, adj, WbT, WAh, Whfrag, Rf, E1h, E2h,
                                            adjbits);
  gat_kernel<<<dim3(64, 8), 256, 0, stream>>>(adjbits, Whfrag, Rf, E1h, E2h, out);
}